// Round 1
// baseline (308.179 us; speedup 1.0000x reference)
//
#include <hip/hip_runtime.h>

#define N_    8
#define C_    256
#define K_    7
#define HID_  10
#define OUTC_ 60
#define S_    16384
#define BN_EPS 1e-5f

// ---- workspace layout (float offsets) ----
#define OFF_ATT  0               // N*K*S = 917504
#define OFF_DEN  917504          // 56 -> pad 64
#define OFF_NUM  917568          // N*C*K = 14336
#define OFF_WQK  931904          // N*C*8 = 16384
#define OFF_EB   948288          // 56 -> pad 64
#define OFF_M2   948352          // N*60*7 = 3360 -> pad 3392
#define OFF_PART 951744          // 256*120 = 30720
#define OFF_SCL  982464          // 64
#define OFF_SHF  982528          // 64
// total ~982592 floats = 3.93 MB

// ---------------- kernel A1: class softmax + den ----------------
__global__ void k_att(const float* __restrict__ seg, float* __restrict__ att,
                      float* __restrict__ den) {
    int idx = blockIdx.x * 256 + threadIdx.x;     // n*S + s
    int n = idx >> 14;
    int s = idx & (S_ - 1);
    const float* sp = seg + (size_t)n * K_ * S_ + s;
    float e[K_];
    float m = -1e30f;
#pragma unroll
    for (int k = 0; k < K_; k++) { e[k] = sp[(size_t)k * S_]; m = fmaxf(m, e[k]); }
    float sum = 0.f;
#pragma unroll
    for (int k = 0; k < K_; k++) { e[k] = __expf(e[k] - m); sum += e[k]; }
    float inv = 1.f / sum;
    float* ap = att + (size_t)n * K_ * S_ + s;
#pragma unroll
    for (int k = 0; k < K_; k++) { float a = e[k] * inv; ap[(size_t)k * S_] = a; e[k] = a; }
    // block-reduce den per k
    __shared__ float red[4][K_];
    int lane = threadIdx.x & 63, wv = threadIdx.x >> 6;
#pragma unroll
    for (int k = 0; k < K_; k++) {
        float v = e[k];
        for (int off = 32; off; off >>= 1) v += __shfl_xor(v, off, 64);
        if (lane == 0) red[wv][k] = v;
    }
    __syncthreads();
    if (threadIdx.x < K_) {
        float v = red[0][threadIdx.x] + red[1][threadIdx.x] + red[2][threadIdx.x] + red[3][threadIdx.x];
        atomicAdd(&den[n * K_ + threadIdx.x], v);
    }
}

// ---------------- kernel A2: num[n,c,k] = sum_s fea*att ----------------
__global__ void k_num(const float* __restrict__ fea, const float* __restrict__ att,
                      float* __restrict__ num) {
    int n = blockIdx.x >> 5;
    int c0 = (blockIdx.x & 31) * 8;
    int tid = threadIdx.x;
    float acc[8][K_] = {};
    const float* ap = att + (size_t)n * K_ * S_;
    const float* fp = fea + ((size_t)n * C_ + c0) * S_;
    for (int s = tid; s < S_; s += 256) {
        float a[K_];
#pragma unroll
        for (int k = 0; k < K_; k++) a[k] = ap[(size_t)k * S_ + s];
#pragma unroll
        for (int c = 0; c < 8; c++) {
            float f = fp[(size_t)c * S_ + s];
#pragma unroll
            for (int k = 0; k < K_; k++) acc[c][k] += f * a[k];
        }
    }
    __shared__ float red[4][56];
    int lane = tid & 63, wv = tid >> 6;
#pragma unroll
    for (int c = 0; c < 8; c++)
#pragma unroll
        for (int k = 0; k < K_; k++) {
            float v = acc[c][k];
            for (int off = 32; off; off >>= 1) v += __shfl_xor(v, off, 64);
            if (lane == 0) red[wv][c * K_ + k] = v;
        }
    __syncthreads();
    if (tid < 56) {
        float v = red[0][tid] + red[1][tid] + red[2][tid] + red[3][tid];
        int c = tid / K_, k = tid % K_;
        num[((size_t)n * C_ + c0 + c) * K_ + k] = v;
    }
}

// ---------------- kernel B: p_center -> query -> Wqk, ebias, M2 ----------------
__global__ void k_center(const float* __restrict__ num, const float* __restrict__ den,
                         const float* __restrict__ Wq, const float* __restrict__ bq,
                         const float* __restrict__ Wk, const float* __restrict__ bk,
                         const float* __restrict__ Wp,
                         float* __restrict__ wqk, float* __restrict__ eb,
                         float* __restrict__ m2) {
    int n = blockIdx.x, tid = threadIdx.x;
    __shared__ float pc[C_ * K_];     // [c][k]
    __shared__ float ql[HID_ * K_];   // [o][k]
    __shared__ float dinv[K_];
    if (tid < K_) dinv[tid] = 1.f / den[n * K_ + tid];
    __syncthreads();
    for (int i = tid; i < C_ * K_; i += 256)
        pc[i] = num[(size_t)n * C_ * K_ + i] * dinv[i % K_];
    __syncthreads();
    if (tid < HID_ * K_) {
        int o = tid / K_, k = tid % K_;
        float s = bq[o];
        for (int c = 0; c < C_; c++) s += Wq[o * C_ + c] * pc[c * K_ + k];
        ql[tid] = s;
    }
    __syncthreads();
    // wqk[n][c][8]: fold query into Wk
    for (int i = tid; i < C_ * 8; i += 256) {
        int c = i >> 3, k = i & 7;
        float s = 0.f;
        if (k < K_)
            for (int o = 0; o < HID_; o++) s += ql[o * K_ + k] * Wk[o * C_ + c];
        wqk[(size_t)n * C_ * 8 + i] = s;
    }
    if (tid < K_) {
        float s = 0.f;
        for (int o = 0; o < HID_; o++) s += ql[o * K_ + tid] * bk[o];
        eb[n * K_ + tid] = s;
    }
    // M2 = Wp2 @ p_center : [60][7]
    for (int i = tid; i < OUTC_ * K_; i += 256) {
        int o = i / K_, k = i % K_;
        float s = 0.f;
        for (int c = 0; c < C_; c++) s += Wp[o * 2 * C_ + C_ + c] * pc[c * K_ + k];
        m2[(size_t)n * OUTC_ * K_ + i] = s;
    }
}

// ---------------- kernel C: fused energy/softmax/projection ----------------
__global__ void __launch_bounds__(256) k_main(
        const float* __restrict__ fea, const float* __restrict__ wp,
        const float* __restrict__ wqk, const float* __restrict__ ebias,
        const float* __restrict__ m2, float* __restrict__ y,
        float* __restrict__ part) {
    int blk = blockIdx.x;
    int n = blk >> 5, tile = blk & 31;
    int tid = threadIdx.x;
    __shared__ float wp_l[C_ * OUTC_];   // [c][60] transposed Wp1 (61440 B)
    __shared__ float m2_l[OUTC_ * K_];   // [o][k]
    __shared__ float redw[4][120];
    __shared__ float eb_l[K_];
    for (int i = tid; i < C_ * OUTC_; i += 256) {
        int c = i / OUTC_, o = i - c * OUTC_;
        wp_l[i] = wp[o * (2 * C_) + c];
    }
    for (int i = tid; i < OUTC_ * K_; i += 256) m2_l[i] = m2[(size_t)n * OUTC_ * K_ + i];
    if (tid < K_) eb_l[tid] = ebias[n * K_ + tid];
    __syncthreads();

    int s0 = tile * 512 + tid * 2;
    const float* fp = fea + (size_t)n * C_ * S_ + s0;
    const float* wq = wqk + (size_t)n * C_ * 8;
    float ya[2][OUTC_];
    float ek[2][K_];
#pragma unroll
    for (int o = 0; o < OUTC_; o++) { ya[0][o] = 0.f; ya[1][o] = 0.f; }
#pragma unroll
    for (int k = 0; k < K_; k++) { ek[0][k] = eb_l[k]; ek[1][k] = eb_l[k]; }

    for (int c = 0; c < C_; c++) {
        float2 f = *(const float2*)(fp + (size_t)c * S_);
#pragma unroll
        for (int k = 0; k < K_; k++) {
            float w = wq[c * 8 + k];            // wave-uniform -> scalar load
            ek[0][k] += w * f.x; ek[1][k] += w * f.y;
        }
#pragma unroll
        for (int o = 0; o < OUTC_; o++) {
            float w = wp_l[c * OUTC_ + o];      // broadcast ds_read_b128 x15
            ya[0][o] += w * f.x; ya[1][o] += w * f.y;
        }
    }
    // softmax over 7 classes + M2 @ attention
#pragma unroll
    for (int j = 0; j < 2; j++) {
        float m = ek[j][0];
#pragma unroll
        for (int k = 1; k < K_; k++) m = fmaxf(m, ek[j][k]);
        float a[K_]; float sum = 0.f;
#pragma unroll
        for (int k = 0; k < K_; k++) { a[k] = __expf(ek[j][k] - m); sum += a[k]; }
        float inv = 1.f / sum;
#pragma unroll
        for (int k = 0; k < K_; k++) a[k] *= inv;
#pragma unroll
        for (int o = 0; o < OUTC_; o++) {
            float s = 0.f;
#pragma unroll
            for (int k = 0; k < K_; k++) s += m2_l[o * K_ + k] * a[k];
            ya[j][o] += s;
        }
    }
    // store pre-BN y (into d_out) + BN partial sums
    float* yp = y + (size_t)n * OUTC_ * S_ + s0;
    int lane = tid & 63, wv = tid >> 6;
#pragma unroll
    for (int o = 0; o < OUTC_; o++) {
        float2 v = make_float2(ya[0][o], ya[1][o]);
        *(float2*)(yp + (size_t)o * S_) = v;
        float sm = v.x + v.y;
        float sq = v.x * v.x + v.y * v.y;
        for (int off = 32; off; off >>= 1) {
            sm += __shfl_xor(sm, off, 64);
            sq += __shfl_xor(sq, off, 64);
        }
        if (lane == 0) { redw[wv][o] = sm; redw[wv][60 + o] = sq; }
    }
    __syncthreads();
    if (tid < 120)
        part[(size_t)blk * 120 + tid] =
            redw[0][tid] + redw[1][tid] + redw[2][tid] + redw[3][tid];
}

// ---------------- kernel D: BN statistics ----------------
__global__ void k_bn(const float* __restrict__ part, const float* __restrict__ gamma,
                     const float* __restrict__ beta, float* __restrict__ scl,
                     float* __restrict__ shf) {
    int tid = threadIdx.x;
    if (tid < OUTC_) {
        float s = 0.f, q = 0.f;
        for (int b = 0; b < 256; b++) {
            s += part[b * 120 + tid];
            q += part[b * 120 + 60 + tid];
        }
        const float invn = 1.f / (float)(N_ * S_);
        float mean = s * invn;
        float var = q * invn - mean * mean;
        float sc = gamma[tid] * rsqrtf(var + BN_EPS);
        scl[tid] = sc;
        shf[tid] = beta[tid] - mean * sc;
    }
}

// ---------------- kernel E: in-place BN apply + ReLU ----------------
__global__ void k_apply(float* __restrict__ y, const float* __restrict__ scl,
                        const float* __restrict__ shf) {
    int idx = blockIdx.x * 256 + threadIdx.x;          // float4 index
    int o = (idx >> 12) % OUTC_;                        // (idx*4 / S) % 60
    float4 v = ((const float4*)y)[idx];
    float a = scl[o], b = shf[o];
    v.x = fmaxf(v.x * a + b, 0.f);
    v.y = fmaxf(v.y * a + b, 0.f);
    v.z = fmaxf(v.z * a + b, 0.f);
    v.w = fmaxf(v.w * a + b, 0.f);
    ((float4*)y)[idx] = v;
}

extern "C" void kernel_launch(void* const* d_in, const int* in_sizes, int n_in,
                              void* d_out, int out_size, void* d_ws, size_t ws_size,
                              hipStream_t stream) {
    const float* p_fea = (const float*)d_in[0];
    const float* p_seg = (const float*)d_in[1];
    const float* Wq    = (const float*)d_in[2];
    const float* bq    = (const float*)d_in[3];
    const float* Wk    = (const float*)d_in[4];
    const float* bk    = (const float*)d_in[5];
    const float* Wp    = (const float*)d_in[6];
    const float* gamma = (const float*)d_in[7];
    const float* beta  = (const float*)d_in[8];

    float* ws   = (float*)d_ws;
    float* att  = ws + OFF_ATT;
    float* den  = ws + OFF_DEN;
    float* num  = ws + OFF_NUM;
    float* wqk  = ws + OFF_WQK;
    float* eb   = ws + OFF_EB;
    float* m2   = ws + OFF_M2;
    float* part = ws + OFF_PART;
    float* scl  = ws + OFF_SCL;
    float* shf  = ws + OFF_SHF;
    float* ybuf = (float*)d_out;   // pre-BN y lives in d_out, finalized in-place

    hipMemsetAsync(den, 0, 64 * sizeof(float), stream);
    k_att<<<512, 256, 0, stream>>>(p_seg, att, den);
    k_num<<<256, 256, 0, stream>>>(p_fea, att, num);
    k_center<<<8, 256, 0, stream>>>(num, den, Wq, bq, Wk, bk, Wp, wqk, eb, m2);
    k_main<<<256, 256, 0, stream>>>(p_fea, Wp, wqk, eb, m2, ybuf, part);
    k_bn<<<1, 64, 0, stream>>>(part, gamma, beta, scl, shf);
    k_apply<<<(N_ * OUTC_ * S_ / 4) / 256, 256, 0, stream>>>(ybuf, scl, shf);
}